// Round 4
// baseline (102.952 us; speedup 1.0000x reference)
//
#include <hip/hip_runtime.h>

typedef unsigned short u16;
typedef unsigned int u32;
typedef __bf16 bf16x8 __attribute__((ext_vector_type(8)));
typedef float f32x4 __attribute__((ext_vector_type(4)));

__device__ __forceinline__ float bf2f(u16 u) { return __uint_as_float(((u32)u) << 16); }
__device__ __forceinline__ u16 f2bf(float f) {
  u32 x = __float_as_uint(f);
  x += 0x7fffu + ((x >> 16) & 1u);
  return (u16)(x >> 16);
}
// monotone float<->uint encoding for atomicMax on floats (finite values)
__device__ __forceinline__ u32 encf(float x) {
  u32 u = __float_as_uint(x);
  return (u >> 31) ? ~u : (u | 0x80000000u);
}
__device__ __forceinline__ float decf(u32 e) {
  return (e >> 31) ? __uint_as_float(e & 0x7fffffffu) : __uint_as_float(~e);
}
// async global->LDS, 16B per lane; lds base must be wave-uniform
__device__ __forceinline__ void gload16(const float* g, void* l) {
  __builtin_amdgcn_global_load_lds((const __attribute__((address_space(1))) void*)g,
                                   (__attribute__((address_space(3))) void*)l, 16, 0, 0);
}

#define MFMA(a, b, c) __builtin_amdgcn_mfma_f32_16x16x32_bf16(a, b, c, 0, 0, 0)

// ---------------------------------------------------------------------------
// prep_w: z=0: Wq->WqT bf16 transposed; z=1: Wk->WkT; z=2: proj->projb copy;
// z=3: x<4&&y<4: WWT[o][i] = sum_d Wo[d][o]*Wv[i][d]  (bf16, from f32 inputs)
//      x==4&&y==0: bw[o] = sum_d bv[d]*Wo[d][o]; zero ksum; zero mxk.
//      x==5: zero kvsW0 (1 MB, for kvso's atomicAdd accumulation).
// ---------------------------------------------------------------------------
__global__ __launch_bounds__(256) void prep_w(
    const float* Wq, const float* Wk, const float* Wv, const float* Wo,
    const float* proj, const float* bv,
    u16* WqT, u16* WkT, u16* projb, u16* WWT, float* bw,
    float* __restrict__ ksum, u32* __restrict__ mxk,
    float* __restrict__ kvsW0) {
  __shared__ u16 tsh[32][33];
  __shared__ u16 As[64][40];
  __shared__ u16 Bs[64][40];
  const int z = blockIdx.z;
  const int x = threadIdx.x, y = threadIdx.y;
  const int tid = y * 32 + x;
  if (z < 2) {
    const float* s = z == 0 ? Wq : Wk;
    u16* d = z == 0 ? WqT : WkT;
    int r0 = blockIdx.y * 32, c0 = blockIdx.x * 32;
#pragma unroll
    for (int i = 0; i < 32; i += 8) tsh[y + i][x] = f2bf(s[(r0 + y + i) * 256 + c0 + x]);
    __syncthreads();
#pragma unroll
    for (int i = 0; i < 32; i += 8) d[(c0 + y + i) * 256 + r0 + x] = tsh[x][y + i];
    return;
  }
  if (z == 2) {
    int r0 = blockIdx.y * 32, c0 = blockIdx.x * 32;
#pragma unroll
    for (int i = 0; i < 32; i += 8)
      projb[(r0 + y + i) * 256 + c0 + x] = f2bf(proj[(r0 + y + i) * 256 + c0 + x]);
    return;
  }
  // z == 3
  if (blockIdx.x < 4 && blockIdx.y < 4) {
    const int o0 = blockIdx.x * 64, i0 = blockIdx.y * 64;
    const int lane = tid & 63, wid = tid >> 6;
    const int wm = (wid >> 1) * 32, wn = (wid & 1) * 32;
    const int fm = lane & 15, fq = (lane >> 4) * 8, rowq = (lane >> 4) * 4;
    const int dr = tid >> 3, oc = (tid & 7) * 8;
    const int ir = tid >> 2, dc = (tid & 3) * 8;
    f32x4 acc[2][2] = {};
    for (int it = 0; it < 8; ++it) {
      int d0 = it * 32;
      float4 w0 = *(const float4*)(Wo + (d0 + dr) * 256 + o0 + oc);
      float4 w1 = *(const float4*)(Wo + (d0 + dr) * 256 + o0 + oc + 4);
      float4 v0 = *(const float4*)(Wv + (i0 + ir) * 256 + d0 + dc);
      float4 v1 = *(const float4*)(Wv + (i0 + ir) * 256 + d0 + dc + 4);
      __syncthreads();
      float wv[8] = {w0.x, w0.y, w0.z, w0.w, w1.x, w1.y, w1.z, w1.w};
#pragma unroll
      for (int j = 0; j < 8; ++j) As[oc + j][dr] = f2bf(wv[j]);
      u16* bp = &Bs[ir][dc];
      bp[0] = f2bf(v0.x); bp[1] = f2bf(v0.y); bp[2] = f2bf(v0.z); bp[3] = f2bf(v0.w);
      bp[4] = f2bf(v1.x); bp[5] = f2bf(v1.y); bp[6] = f2bf(v1.z); bp[7] = f2bf(v1.w);
      __syncthreads();
      bf16x8 a0 = *(const bf16x8*)&As[wm + fm][fq];
      bf16x8 a1 = *(const bf16x8*)&As[wm + 16 + fm][fq];
      bf16x8 b0 = *(const bf16x8*)&Bs[wn + fm][fq];
      bf16x8 b1 = *(const bf16x8*)&Bs[wn + 16 + fm][fq];
      acc[0][0] = MFMA(a0, b0, acc[0][0]);
      acc[0][1] = MFMA(a0, b1, acc[0][1]);
      acc[1][0] = MFMA(a1, b0, acc[1][0]);
      acc[1][1] = MFMA(a1, b1, acc[1][1]);
    }
#pragma unroll
    for (int mt = 0; mt < 2; ++mt)
#pragma unroll
      for (int nt = 0; nt < 2; ++nt)
#pragma unroll
        for (int r = 0; r < 4; ++r)
          WWT[(o0 + wm + mt * 16 + rowq + r) * 256 + i0 + wn + nt * 16 + fm] =
              f2bf(acc[mt][nt][r]);
    return;
  }
  if (blockIdx.x == 4 && blockIdx.y == 0) {
    float s = 0.0f;
    for (int d = 0; d < 256; ++d) s = fmaf(bv[d], Wo[d * 256 + tid], s);
    bw[tid] = s;
    for (int i = tid; i < 1024; i += 256) ksum[i] = 0.0f;
    if (tid < 4) mxk[tid] = 0u;
    return;
  }
  if (blockIdx.x == 5) {
    // zero kvsW0: 8 blocks (y=0..7) x 256 thr x 32 float4 = 1 MB, coalesced
    float4 z4 = {0.0f, 0.0f, 0.0f, 0.0f};
    float4* p = (float4*)kvsW0 + blockIdx.y * 8192;
#pragma unroll
    for (int i = 0; i < 32; ++i) p[i * 256 + tid] = z4;
  }
}

// ---------------------------------------------------------------------------
// projrot2: z=0 key, z=1 query, z=2 value. 32-row tiles, 768 blocks.
//  - mode 0 (k): GEMM1(Wk) -> rotary -> GEMM2(projb) -> xp f32 + diag_k +
//    per-batch atomicMax (global max across L and M -> two-pass stays).
//  - mode 1 (q): same through GEMM2, then FUSED softmax-kernel: row-max over
//    M is block-local -> qp = bf16(0.0625*(exp(.-diag-rowmax)+eps)) direct.
//  - mode 2 (v): GEMM1 only, W = WWT (=Wo^T.Wv fold), no bias/rotary ->
//    xvw = bf16(value @ WWT^T). Lands in the fill-gated window.
// ---------------------------------------------------------------------------
__global__ __launch_bounds__(256, 2) void projrot2(
    const float* __restrict__ Xq, const float* __restrict__ Xk,
    const float* __restrict__ Xv,
    const u16* __restrict__ WqT, const u16* __restrict__ WkT,
    const u16* __restrict__ WWT,
    const float* __restrict__ bq, const float* __restrict__ bk,
    const float* __restrict__ pos, const u16* __restrict__ projb,
    float* __restrict__ diag_k, u16* __restrict__ qp,
    float* __restrict__ xp, u16* __restrict__ xvw, u32* __restrict__ mxk) {
  const int mode = blockIdx.z;  // 0=k, 1=q, 2=v
  const float* X = mode == 0 ? Xk : (mode == 1 ? Xq : Xv);
  const u16* W = mode == 0 ? WkT : (mode == 1 ? WqT : WWT);
  __shared__ float posl[32][256];  // 32 KB pos tile
  __shared__ u16 cbuf[32][264];    // 16.9 KB; row stride 528 B
  __shared__ float dred[2][32];
  __shared__ float mred[2][32];
  __shared__ float wred[4];
  const int row0 = blockIdx.x * 32;
  const int l0 = row0 & 2047;
  const int t = threadIdx.x;
  const int lane = t & 63, wid = t >> 6;
  const int wrow = wid & 1, wcol = wid >> 1;  // 16 rows x 128 cols per wave
  const int fm = lane & 15, fq = (lane >> 4) * 8, rowq = (lane >> 4) * 4;

  // ---- stage pos tile via async global->LDS (completes under GEMM1) ----
  if (mode < 2) {
#pragma unroll
    for (int i = 0; i < 8; ++i) {
      const int pr = i * 4 + wid;  // wave-uniform row
      gload16(pos + (long long)(l0 + pr) * 256 + lane * 4, &posl[pr][0]);
    }
  }

  // ---- hoist per-lane A row (full K) and convert to bf16 ----
  const float* a0p = X + (long long)(row0 + wrow * 16 + fm) * 256 + fq;
  bf16x8 aF[8];
#pragma unroll
  for (int it = 0; it < 8; ++it) {
    float4 p0 = *(const float4*)(a0p + it * 32);
    float4 p1 = *(const float4*)(a0p + it * 32 + 4);
    u16 ab[8] = {f2bf(p0.x), f2bf(p0.y), f2bf(p0.z), f2bf(p0.w),
                 f2bf(p1.x), f2bf(p1.y), f2bf(p1.z), f2bf(p1.w)};
    aF[it] = *(const bf16x8*)ab;
  }

  // ---- GEMM1: X @ W^T, B register-double-buffered (lookahead 1) ----
  const u16* wp = W + (long long)(wcol * 128 + fm) * 256 + fq;
  f32x4 acc[8] = {};
  bf16x8 bb[2][8];
#pragma unroll
  for (int j = 0; j < 8; ++j) bb[0][j] = *(const bf16x8*)(wp + j * 4096);
#pragma unroll
  for (int it = 0; it < 8; ++it) {
    if (it < 7) {
#pragma unroll
      for (int j = 0; j < 8; ++j)
        bb[(it + 1) & 1][j] = *(const bf16x8*)(wp + j * 4096 + (it + 1) * 32);
    }
#pragma unroll
    for (int j = 0; j < 8; ++j) acc[j] = MFMA(aF[it], bb[it & 1][j], acc[j]);
  }

  if (mode == 2) {
    // ---- v: write xvw = bf16(value @ WWT^T), no bias/rotary/GEMM2 ----
#pragma unroll
    for (int j = 0; j < 8; ++j) {
      const int col = wcol * 128 + j * 16 + fm;
#pragma unroll
      for (int r = 0; r < 4; ++r)
        xvw[(long long)(row0 + wrow * 16 + rowq + r) * 256 + col] = f2bf(acc[j][r]);
    }
    return;
  }

  // ---- epilogue: bias into acc, diag partials (pre-rotary) ----
  const float* bias = mode ? bq : bk;
  float dsum[4] = {};
#pragma unroll
  for (int j = 0; j < 8; ++j) {
    float bb2 = bias[wcol * 128 + j * 16 + fm];
#pragma unroll
    for (int r = 0; r < 4; ++r) {
      float v = acc[j][r] + bb2;
      acc[j][r] = v;
      dsum[r] += v * v;
    }
  }
#pragma unroll
  for (int o = 1; o < 16; o <<= 1)
#pragma unroll
    for (int r = 0; r < 4; ++r) dsum[r] += __shfl_xor(dsum[r], o, 64);
  if (fm == 0) {
#pragma unroll
    for (int r = 0; r < 4; ++r) dred[wcol][wrow * 16 + rowq + r] = dsum[r];
  }
  __syncthreads();  // dred visible; posl staging drained
  if (mode == 0 && t < 32) diag_k[row0 + t] = 0.03125f * (dred[0][t] + dred[1][t]);

  // ---- rotary in registers (partner col = lane^1), pos from LDS ----
#pragma unroll
  for (int j = 0; j < 8; ++j) {
    const int c = wcol * 128 + j * 16 + fm;
#pragma unroll
    for (int r = 0; r < 4; ++r) {
      const int row = wrow * 16 + rowq + r;
      float v = acc[j][r];
      float prt = __shfl_xor(v, 1, 64);
      float x2 = (fm & 1) ? prt : -prt;
      float2 cs = *(const float2*)&posl[row][c & ~1];
      // cs.x = sin (even col), cs.y = cos (odd col)
      cbuf[row][c] = f2bf(0.25f * (v * cs.y + x2 * cs.x));
    }
  }
  // issue GEMM2's first B set before the barrier (drain absorbs latency)
  const u16* pp = projb + (long long)(wcol * 128 + fm) * 256 + fq;
  bf16x8 b2[2][8];
#pragma unroll
  for (int j = 0; j < 8; ++j) b2[0][j] = *(const bf16x8*)(pp + j * 4096);
  __syncthreads();

  // ---- GEMM2: cbuf(rotated) @ projb^T, B register dbuf (lookahead 1) ----
  f32x4 acc2[8] = {};
#pragma unroll
  for (int it = 0; it < 8; ++it) {
    const int k0 = it * 32;
    bf16x8 af = *(const bf16x8*)&cbuf[wrow * 16 + fm][k0 + fq];
    if (it < 7) {
#pragma unroll
      for (int j = 0; j < 8; ++j)
        b2[(it + 1) & 1][j] = *(const bf16x8*)(pp + j * 4096 + (it + 1) * 32);
    }
#pragma unroll
    for (int j = 0; j < 8; ++j) acc2[j] = MFMA(af, b2[it & 1][j], acc2[j]);
  }

  if (mode == 1) {
    // ---- fused q softmax-kernel: row max over M, exp, bf16 store ----
    float m4[4] = {-3.0e38f, -3.0e38f, -3.0e38f, -3.0e38f};
#pragma unroll
    for (int j = 0; j < 8; ++j)
#pragma unroll
      for (int r = 0; r < 4; ++r) m4[r] = fmaxf(m4[r], acc2[j][r]);
#pragma unroll
    for (int o = 1; o < 16; o <<= 1)
#pragma unroll
      for (int r = 0; r < 4; ++r) m4[r] = fmaxf(m4[r], __shfl_xor(m4[r], o, 64));
    if (fm == 0) {
#pragma unroll
      for (int r = 0; r < 4; ++r) mred[wcol][wrow * 16 + rowq + r] = m4[r];
    }
    __syncthreads();
#pragma unroll
    for (int j = 0; j < 8; ++j) {
      const int col = wcol * 128 + j * 16 + fm;
#pragma unroll
      for (int r = 0; r < 4; ++r) {
        const int row = wrow * 16 + rowq + r;
        float mxr = fmaxf(mred[0][row], mred[1][row]);
        float dgr = 0.03125f * (dred[0][row] + dred[1][row]);
        float v = 0.0625f * (__expf(acc2[j][r] - dgr - mxr) + 1e-6f);
        qp[(long long)(row0 + row) * 256 + col] = f2bf(v);
      }
    }
  } else {
    // ---- k: write xp f32 + per-batch max for the global-max pass ----
    float mx = -3.0e38f;
#pragma unroll
    for (int j = 0; j < 8; ++j) {
      int col = wcol * 128 + j * 16 + fm;
#pragma unroll
      for (int r = 0; r < 4; ++r) {
        float v = acc2[j][r];
        xp[(long long)(row0 + wrow * 16 + rowq + r) * 256 + col] = v;
        mx = fmaxf(mx, v);
      }
    }
#pragma unroll
    for (int o = 32; o > 0; o >>= 1) mx = fmaxf(mx, __shfl_xor(mx, o, 64));
    if (lane == 0) wred[wid] = mx;
    __syncthreads();
    if (t == 0) {
      float m = fmaxf(fmaxf(wred[0], wred[1]), fmaxf(wred[2], wred[3]));
      atomicMax(mxk + (row0 >> 11), encf(m));
    }
  }
}

// ---------------------------------------------------------------------------
// kvso: kvsW0[b][o][m] += sum_l XvWT[l][o] * kp[l][m] over 256-row L-chunks,
// accumulated via f32 atomicAdd (kvsW0 zeroed by prep_w). kp = exp(xp-diag-mx)
// fused in transpose-staging; XvWT read bf16. ksum by ox==0 blocks.
// grid (4 ox, 4 my, 32 = b*8+kc) = 512 blocks -> 2 blocks/CU.
// Replaces kvs_raw_split + kvsw (bw*ksum term cancels into +bw at numout).
// ---------------------------------------------------------------------------
__global__ __launch_bounds__(256, 2) void kvso(
    const float* __restrict__ xp, const u16* __restrict__ xvw,
    const float* __restrict__ diag_k, const u32* __restrict__ mxk,
    float* __restrict__ kvsW0, float* __restrict__ ksum) {
  __shared__ union USM {
    struct { u16 As[64][40]; u16 Bs[64][40]; } s;
    float ksbuf[32][65];
  } sm;
  const int ox = blockIdx.x, my = blockIdx.y, z = blockIdx.z;
  const int b = z >> 3, kc = z & 7;
  const long long l0 = (long long)b * 2048 + kc * 256;
  const int t = threadIdx.x;
  const int lane = t & 63, wid = t >> 6;
  const int wrow = wid >> 1, wcol = wid & 1;
  const int fm = lane & 15, fq = (lane >> 4) * 8, rowq = (lane >> 4) * 4;
  const float mxv = decf(mxk[b]);
  const int sr = t >> 3, sc = (t & 7) * 8;
  f32x4 acc[2][2] = {};
  float ksp[8] = {};
  long long lrow = l0 + sr;
  float4 x0 = *(const float4*)(xp + lrow * 256 + my * 64 + sc);
  float4 x1 = *(const float4*)(xp + lrow * 256 + my * 64 + sc + 4);
  uint4 va = *(const uint4*)(xvw + lrow * 256 + ox * 64 + sc);
  float dgl = diag_k[lrow];
  for (int s = 0; s < 8; ++s) {
    float xv[8] = {x0.x, x0.y, x0.z, x0.w, x1.x, x1.y, x1.z, x1.w};
    u32 vu[4] = {va.x, va.y, va.z, va.w};
    u16 kpv[8];
#pragma unroll
    for (int j = 0; j < 8; ++j) {
      float v = 0.0625f * (__expf(xv[j] - dgl - mxv) + 1e-6f);
      kpv[j] = f2bf(v);
      ksp[j] += bf2f(kpv[j]);
    }
    __syncthreads();
#pragma unroll
    for (int j = 0; j < 4; ++j) {
      sm.s.As[sc + 2 * j][sr] = (u16)(vu[j] & 0xffffu);
      sm.s.As[sc + 2 * j + 1][sr] = (u16)(vu[j] >> 16);
    }
#pragma unroll
    for (int j = 0; j < 8; ++j) sm.s.Bs[sc + j][sr] = kpv[j];
    __syncthreads();
    if (s < 7) {
      lrow = l0 + (s + 1) * 32 + sr;
      x0 = *(const float4*)(xp + lrow * 256 + my * 64 + sc);
      x1 = *(const float4*)(xp + lrow * 256 + my * 64 + sc + 4);
      va = *(const uint4*)(xvw + lrow * 256 + ox * 64 + sc);
      dgl = diag_k[lrow];
    }
    bf16x8 a0 = *(const bf16x8*)&sm.s.As[wrow * 32 + fm][fq];
    bf16x8 a1 = *(const bf16x8*)&sm.s.As[wrow * 32 + 16 + fm][fq];
    bf16x8 b0 = *(const bf16x8*)&sm.s.Bs[wcol * 32 + fm][fq];
    bf16x8 b1 = *(const bf16x8*)&sm.s.Bs[wcol * 32 + 16 + fm][fq];
    acc[0][0] = MFMA(a0, b0, acc[0][0]);
    acc[0][1] = MFMA(a0, b1, acc[0][1]);
    acc[1][0] = MFMA(a1, b0, acc[1][0]);
    acc[1][1] = MFMA(a1, b1, acc[1][1]);
  }
  // accumulate into kvsW0[b][o][m] (coalesced over m = fm)
#pragma unroll
  for (int mt = 0; mt < 2; ++mt)
#pragma unroll
    for (int nt = 0; nt < 2; ++nt)
#pragma unroll
      for (int r = 0; r < 4; ++r)
        atomicAdd(kvsW0 + (long long)b * 65536 +
                      (long long)(ox * 64 + wrow * 32 + mt * 16 + rowq + r) * 256 +
                      my * 64 + wcol * 32 + nt * 16 + fm,
                  acc[mt][nt][r]);
  __syncthreads();
#pragma unroll
  for (int j = 0; j < 8; ++j) sm.ksbuf[sr][sc + j] = ksp[j];
  __syncthreads();
  if (ox == 0 && t < 64) {
    float ssum = 0.0f;
    for (int r = 0; r < 32; ++r) ssum += sm.ksbuf[r][t];
    atomicAdd(ksum + b * 256 + my * 64 + t, ssum);
  }
}

// ---------------------------------------------------------------------------
// numout: out = (qp @ kvsW0^T)/den + bw + bo.  qp bf16 precomputed; kvsW0
// f32 (L2-hot 1 MB/batch) converted to bf16 fragments inline (register dbuf).
// den from qp and ksum (bw*ksum GEMM term cancels to +bw exactly).
// 16-row tiles, grid (128,1,4), 4 blocks/CU.
// ---------------------------------------------------------------------------
__global__ __launch_bounds__(256, 4) void numout(
    const u16* __restrict__ qp, const float* __restrict__ ksum,
    const float* __restrict__ kvsW0, const float* __restrict__ bw,
    const float* __restrict__ bo, float* __restrict__ out) {
  __shared__ float ksm[256], dsh[16];
  const int row0 = blockIdx.x * 16;
  const int b = blockIdx.z;
  const long long qrow = (long long)b * 2048 + row0;
  const int t = threadIdx.x;
  const int lane = t & 63, wid = t >> 6;
  const int fm = lane & 15, fq = (lane >> 4) * 8, rowq = (lane >> 4) * 4;

  // A frags: direct per-lane global loads, all 8 K-steps hoisted
  const u16* qa = qp + (qrow + fm) * 256 + fq;
  bf16x8 af[8];
#pragma unroll
  for (int it = 0; it < 8; ++it) af[it] = *(const bf16x8*)(qa + it * 32);

  // B first buffer (register dbuf, lookahead 1), f32 source -> bf16
  const float* kvb = kvsW0 + (long long)b * 65536 + (long long)(wid * 64 + fm) * 256 + fq;
  bf16x8 bb[2][4];
#pragma unroll
  for (int j = 0; j < 4; ++j) {
    float4 c0 = *(const float4*)(kvb + j * 4096);
    float4 c1 = *(const float4*)(kvb + j * 4096 + 4);
    u16 tb[8] = {f2bf(c0.x), f2bf(c0.y), f2bf(c0.z), f2bf(c0.w),
                 f2bf(c1.x), f2bf(c1.y), f2bf(c1.z), f2bf(c1.w)};
    bb[0][j] = *(const bf16x8*)tb;
  }

  // den inputs
  ksm[t] = ksum[b * 256 + t];
  const int prow = t >> 4, pc0 = (t & 15) * 16;
  const u16* qr = qp + (qrow + prow) * 256 + pc0;
  uint4 u0 = *(const uint4*)(qr);
  uint4 u1 = *(const uint4*)(qr + 8);
  __syncthreads();  // ksm visible

  float denp = 0.0f;
  u32 uu[8] = {u0.x, u0.y, u0.z, u0.w, u1.x, u1.y, u1.z, u1.w};
#pragma unroll
  for (int j = 0; j < 8; ++j) {
    denp += bf2f((u16)(uu[j] & 0xffffu)) * ksm[pc0 + 2 * j];
    denp += bf2f((u16)(uu[j] >> 16)) * ksm[pc0 + 2 * j + 1];
  }
#pragma unroll
  for (int o = 1; o < 16; o <<= 1) denp += __shfl_xor(denp, o, 64);
  if ((t & 15) == 0) dsh[prow] = denp;

  // GEMM
  f32x4 acc[4] = {};
#pragma unroll
  for (int it = 0; it < 8; ++it) {
    if (it < 7) {
#pragma unroll
      for (int j = 0; j < 4; ++j) {
        float4 c0 = *(const float4*)(kvb + j * 4096 + (it + 1) * 32);
        float4 c1 = *(const float4*)(kvb + j * 4096 + (it + 1) * 32 + 4);
        u16 tb[8] = {f2bf(c0.x), f2bf(c0.y), f2bf(c0.z), f2bf(c0.w),
                     f2bf(c1.x), f2bf(c1.y), f2bf(c1.z), f2bf(c1.w)};
        bb[(it + 1) & 1][j] = *(const bf16x8*)tb;
      }
    }
#pragma unroll
    for (int j = 0; j < 4; ++j) acc[j] = MFMA(af[it], bb[it & 1][j], acc[j]);
  }
  __syncthreads();  // dsh visible
#pragma unroll
  for (int j = 0; j < 4; ++j) {
    int col = wid * 64 + j * 16 + fm;
    float bb2 = bo[col] + bw[col];
#pragma unroll
    for (int r = 0; r < 4; ++r) {
      int l = rowq + r;
      out[(qrow + l) * 256 + col] = acc[j][r] / dsh[l] + bb2;
    }
  }
}

// ---------------------------------------------------------------------------
extern "C" void kernel_launch(void* const* d_in, const int* in_sizes, int n_in,
                              void* d_out, int out_size, void* d_ws, size_t ws_size,
                              hipStream_t stream) {
  (void)in_sizes; (void)n_in; (void)out_size; (void)ws_size;
  const float* query = (const float*)d_in[0];
  const float* key = (const float*)d_in[1];
  const float* value = (const float*)d_in[2];
  // d_in[3] = mask: all-ones, unused
  const float* Wq = (const float*)d_in[4];
  const float* bq = (const float*)d_in[5];
  const float* Wk = (const float*)d_in[6];
  const float* bk = (const float*)d_in[7];
  const float* Wv = (const float*)d_in[8];
  const float* bv = (const float*)d_in[9];
  const float* Wo = (const float*)d_in[10];
  const float* bo = (const float*)d_in[11];
  const float* proj = (const float*)d_in[12];
  const float* pos = (const float*)d_in[13];

  char* w = (char*)d_ws;  // ~26.1 MB used
  u16* qp = (u16*)(w);                        // 4 MB (bf16 q-features)
  float* xp = (float*)(w + (8 << 20));        // 8 MB (k-features f32)
  u16* xvw = (u16*)(w + (16 << 20));          // 4 MB (bf16 value@WWT^T)
  float* kvsW0 = (float*)(w + (20 << 20));    // 1 MB (f32 atomic accum)
  u16* WqT = (u16*)(w + (25 << 20));          // 128 KB each
  u16* WkT = WqT + 65536;
  u16* projb = WkT + 65536;
  u16* WWT = projb + 65536;
  float* diag_k = (float*)(w + (26 << 20));   // 32 KB
  float* ksum = diag_k + 8192;                // 4 KB
  float* bw = ksum + 1024;                    // 1 KB
  u32* mxk = (u32*)(bw + 256);                // 16 B

  prep_w<<<dim3(8, 8, 4), dim3(32, 8), 0, stream>>>(Wq, Wk, Wv, Wo, proj, bv,
                                                    WqT, WkT, projb, WWT, bw,
                                                    ksum, mxk, kvsW0);
  projrot2<<<dim3(256, 1, 3), dim3(256), 0, stream>>>(
      query, key, value, WqT, WkT, WWT, bq, bk, pos, projb, diag_k, qp, xp,
      xvw, mxk);
  kvso<<<dim3(4, 4, 32), dim3(256), 0, stream>>>(xp, xvw, diag_k, mxk, kvsW0,
                                                 ksum);
  numout<<<dim3(128, 1, 4), dim3(256), 0, stream>>>(qp, ksum, kvsW0, bw, bo,
                                                    (float*)d_out);
}

// Round 5
// 81.773 us; speedup vs baseline: 1.2590x; 1.2590x over previous
//
#include <hip/hip_runtime.h>

typedef unsigned short u16;
typedef unsigned int u32;
typedef __bf16 bf16x8 __attribute__((ext_vector_type(8)));
typedef float f32x4 __attribute__((ext_vector_type(4)));

__device__ __forceinline__ float bf2f(u16 u) { return __uint_as_float(((u32)u) << 16); }
__device__ __forceinline__ u16 f2bf(float f) {
  u32 x = __float_as_uint(f);
  x += 0x7fffu + ((x >> 16) & 1u);
  return (u16)(x >> 16);
}
// monotone float<->uint encoding for atomicMax on floats (finite values)
__device__ __forceinline__ u32 encf(float x) {
  u32 u = __float_as_uint(x);
  return (u >> 31) ? ~u : (u | 0x80000000u);
}
__device__ __forceinline__ float decf(u32 e) {
  return (e >> 31) ? __uint_as_float(e & 0x7fffffffu) : __uint_as_float(~e);
}

#define MFMA(a, b, c) __builtin_amdgcn_mfma_f32_16x16x32_bf16(a, b, c, 0, 0, 0)

// ---------------------------------------------------------------------------
// prep_w: z=0: Wq->WqT bf16 transposed; z=1: Wk->WkT; z=2: proj->projb copy;
// z=3: x<4&&y<4: WWT[o][i] = sum_d Wo[d][o]*Wv[i][d]  (bf16, from f32 inputs)
//      x==4&&y==0: bw[o] = sum_d bv[d]*Wo[d][o]; zero ksum; zero mxk.
// ---------------------------------------------------------------------------
__global__ __launch_bounds__(256) void prep_w(
    const float* Wq, const float* Wk, const float* Wv, const float* Wo,
    const float* proj, const float* bv,
    u16* WqT, u16* WkT, u16* projb, u16* WWT, float* bw,
    float* __restrict__ ksum, u32* __restrict__ mxk) {
  __shared__ u16 tsh[32][33];
  __shared__ u16 As[64][40];
  __shared__ u16 Bs[64][40];
  const int z = blockIdx.z;
  const int x = threadIdx.x, y = threadIdx.y;
  const int tid = y * 32 + x;
  if (z < 2) {
    const float* s = z == 0 ? Wq : Wk;
    u16* d = z == 0 ? WqT : WkT;
    int r0 = blockIdx.y * 32, c0 = blockIdx.x * 32;
#pragma unroll
    for (int i = 0; i < 32; i += 8) tsh[y + i][x] = f2bf(s[(r0 + y + i) * 256 + c0 + x]);
    __syncthreads();
#pragma unroll
    for (int i = 0; i < 32; i += 8) d[(c0 + y + i) * 256 + r0 + x] = tsh[x][y + i];
    return;
  }
  if (z == 2) {
    int r0 = blockIdx.y * 32, c0 = blockIdx.x * 32;
#pragma unroll
    for (int i = 0; i < 32; i += 8)
      projb[(r0 + y + i) * 256 + c0 + x] = f2bf(proj[(r0 + y + i) * 256 + c0 + x]);
    return;
  }
  // z == 3
  if (blockIdx.x < 4 && blockIdx.y < 4) {
    const int o0 = blockIdx.x * 64, i0 = blockIdx.y * 64;
    const int lane = tid & 63, wid = tid >> 6;
    const int wm = (wid >> 1) * 32, wn = (wid & 1) * 32;
    const int fm = lane & 15, fq = (lane >> 4) * 8, rowq = (lane >> 4) * 4;
    const int dr = tid >> 3, oc = (tid & 7) * 8;
    const int ir = tid >> 2, dc = (tid & 3) * 8;
    f32x4 acc[2][2] = {};
    for (int it = 0; it < 8; ++it) {
      int d0 = it * 32;
      float4 w0 = *(const float4*)(Wo + (d0 + dr) * 256 + o0 + oc);
      float4 w1 = *(const float4*)(Wo + (d0 + dr) * 256 + o0 + oc + 4);
      float4 v0 = *(const float4*)(Wv + (i0 + ir) * 256 + d0 + dc);
      float4 v1 = *(const float4*)(Wv + (i0 + ir) * 256 + d0 + dc + 4);
      __syncthreads();
      float wv[8] = {w0.x, w0.y, w0.z, w0.w, w1.x, w1.y, w1.z, w1.w};
#pragma unroll
      for (int j = 0; j < 8; ++j) As[oc + j][dr] = f2bf(wv[j]);
      u16* bp = &Bs[ir][dc];
      bp[0] = f2bf(v0.x); bp[1] = f2bf(v0.y); bp[2] = f2bf(v0.z); bp[3] = f2bf(v0.w);
      bp[4] = f2bf(v1.x); bp[5] = f2bf(v1.y); bp[6] = f2bf(v1.z); bp[7] = f2bf(v1.w);
      __syncthreads();
      bf16x8 a0 = *(const bf16x8*)&As[wm + fm][fq];
      bf16x8 a1 = *(const bf16x8*)&As[wm + 16 + fm][fq];
      bf16x8 b0 = *(const bf16x8*)&Bs[wn + fm][fq];
      bf16x8 b1 = *(const bf16x8*)&Bs[wn + 16 + fm][fq];
      acc[0][0] = MFMA(a0, b0, acc[0][0]);
      acc[0][1] = MFMA(a0, b1, acc[0][1]);
      acc[1][0] = MFMA(a1, b0, acc[1][0]);
      acc[1][1] = MFMA(a1, b1, acc[1][1]);
    }
#pragma unroll
    for (int mt = 0; mt < 2; ++mt)
#pragma unroll
      for (int nt = 0; nt < 2; ++nt)
#pragma unroll
        for (int r = 0; r < 4; ++r)
          WWT[(o0 + wm + mt * 16 + rowq + r) * 256 + i0 + wn + nt * 16 + fm] =
              f2bf(acc[mt][nt][r]);
    return;
  }
  if (blockIdx.x == 4 && blockIdx.y == 0) {
    float s = 0.0f;
    for (int d = 0; d < 256; ++d) s = fmaf(bv[d], Wo[d * 256 + tid], s);
    bw[tid] = s;
    for (int i = tid; i < 1024; i += 256) ksum[i] = 0.0f;
    if (tid < 4) mxk[tid] = 0u;
  }
}

// ---------------------------------------------------------------------------
// projrot2: z=0 key, z=1 query. 32-row tiles, grid (256,1,2).
// EXPERIMENT (round 5): both GEMM operands via LDS (kvsw mold) — reg-load
// chunk -> barrier -> LDS write -> barrier -> ds_read_b128 -> MFMA, with the
// next chunk's global loads issued under the MFMAs. This ablates the
// B-direct-global pattern that every slow variant shared.
//  - mode 0 (k): xp f32 + diag_k + per-batch atomicMax.
//  - mode 1 (q): fused softmax-kernel -> qp bf16 (row-max block-local).
// ---------------------------------------------------------------------------
__global__ __launch_bounds__(256, 3) void projrot2(
    const float* __restrict__ Xq, const float* __restrict__ Xk,
    const u16* __restrict__ WqT, const u16* __restrict__ WkT,
    const float* __restrict__ bq, const float* __restrict__ bk,
    const float* __restrict__ pos, const u16* __restrict__ projb,
    float* __restrict__ diag_k, u16* __restrict__ qp,
    float* __restrict__ xp, u32* __restrict__ mxk) {
  const int mode = blockIdx.z;  // 0=k, 1=q
  const float* X = mode ? Xq : Xk;
  const u16* W = mode ? WqT : WkT;  // [outcol][k] bf16
  const float* bias = mode ? bq : bk;
  __shared__ u16 As[32][40];    // 2.5 KB: X chunk (32 rows x 32 k)
  __shared__ u16 Bs[256][40];   // 20 KB: W/proj chunk (256 cols x 32 k)
  __shared__ u16 cbuf[32][264]; // 16.9 KB rotated bf16
  __shared__ float dred[2][32];
  __shared__ float mred[2][32];
  __shared__ float wred[4];
  const int row0 = blockIdx.x * 32;
  const int t = threadIdx.x;
  const int lane = t & 63, wid = t >> 6;
  const int wrow = wid & 1, wcol = wid >> 1;  // 16 rows x 128 cols per wave
  const int fm = lane & 15, fq = (lane >> 4) * 8, rowq = (lane >> 4) * 4;
  // staging indices
  const int ar = t >> 3, ak = (t & 7) * 4;  // A: row, k-quad

  // ---- GEMM1: X @ W^T, both operands staged through LDS ----
  f32x4 acc[8] = {};
  float4 av = *(const float4*)(X + (long long)(row0 + ar) * 256 + ak);
  uint4 bv0 = ((const uint4*)(W + (long long)t * 256))[0];
  uint4 bv1 = ((const uint4*)(W + (long long)t * 256))[1];
  uint4 bv2 = ((const uint4*)(W + (long long)t * 256))[2];
  uint4 bv3 = ((const uint4*)(W + (long long)t * 256))[3];
  for (int s = 0; s < 8; ++s) {
    __syncthreads();  // prev-iter ds_reads done
    As[ar][ak] = f2bf(av.x); As[ar][ak + 1] = f2bf(av.y);
    As[ar][ak + 2] = f2bf(av.z); As[ar][ak + 3] = f2bf(av.w);
    uint4* bsp = (uint4*)&Bs[t][0];
    bsp[0] = bv0; bsp[1] = bv1; bsp[2] = bv2; bsp[3] = bv3;
    __syncthreads();  // staging visible
    if (s < 7) {
      const int k1 = (s + 1) * 32;
      av = *(const float4*)(X + (long long)(row0 + ar) * 256 + k1 + ak);
      const uint4* wn = (const uint4*)(W + (long long)t * 256 + k1);
      bv0 = wn[0]; bv1 = wn[1]; bv2 = wn[2]; bv3 = wn[3];
    }
    bf16x8 af = *(const bf16x8*)&As[wrow * 16 + fm][fq];
#pragma unroll
    for (int j = 0; j < 8; ++j) {
      bf16x8 bf = *(const bf16x8*)&Bs[wcol * 128 + j * 16 + fm][fq];
      acc[j] = MFMA(af, bf, acc[j]);
    }
  }

  // ---- epilogue: bias into acc, diag partials (pre-rotary) ----
  float dsum[4] = {};
#pragma unroll
  for (int j = 0; j < 8; ++j) {
    float bb2 = bias[wcol * 128 + j * 16 + fm];
#pragma unroll
    for (int r = 0; r < 4; ++r) {
      float v = acc[j][r] + bb2;
      acc[j][r] = v;
      dsum[r] += v * v;
    }
  }
#pragma unroll
  for (int o = 1; o < 16; o <<= 1)
#pragma unroll
    for (int r = 0; r < 4; ++r) dsum[r] += __shfl_xor(dsum[r], o, 64);
  if (fm == 0) {
#pragma unroll
    for (int r = 0; r < 4; ++r) dred[wcol][wrow * 16 + rowq + r] = dsum[r];
  }
  __syncthreads();  // dred visible
  if (mode == 0 && t < 32) diag_k[row0 + t] = 0.03125f * (dred[0][t] + dred[1][t]);

  // ---- rotary in registers (partner col = lane^1), pos direct global ----
#pragma unroll
  for (int j = 0; j < 8; ++j) {
    const int c = wcol * 128 + j * 16 + fm;
#pragma unroll
    for (int r = 0; r < 4; ++r) {
      const int row = wrow * 16 + rowq + r;
      const int l = (row0 + row) & 2047;
      float v = acc[j][r];
      float prt = __shfl_xor(v, 1, 64);
      float x2 = (fm & 1) ? prt : -prt;
      float2 cs = *(const float2*)(pos + (long long)l * 256 + (c & ~1));
      // cs.x = sin (even col), cs.y = cos (odd col)
      cbuf[row][c] = f2bf(0.25f * (v * cs.y + x2 * cs.x));
    }
  }

  // ---- GEMM2: cbuf(rotated) @ projb^T, B staged through LDS (reuse Bs) ----
  f32x4 acc2[8] = {};
  uint4 pv0 = ((const uint4*)(projb + (long long)t * 256))[0];
  uint4 pv1 = ((const uint4*)(projb + (long long)t * 256))[1];
  uint4 pv2 = ((const uint4*)(projb + (long long)t * 256))[2];
  uint4 pv3 = ((const uint4*)(projb + (long long)t * 256))[3];
  for (int s = 0; s < 8; ++s) {
    __syncthreads();  // prev-iter ds_reads done (and cbuf writes on s=0)
    uint4* bsp = (uint4*)&Bs[t][0];
    bsp[0] = pv0; bsp[1] = pv1; bsp[2] = pv2; bsp[3] = pv3;
    __syncthreads();  // staging visible
    if (s < 7) {
      const uint4* pn = (const uint4*)(projb + (long long)t * 256 + (s + 1) * 32);
      pv0 = pn[0]; pv1 = pn[1]; pv2 = pn[2]; pv3 = pn[3];
    }
    bf16x8 af = *(const bf16x8*)&cbuf[wrow * 16 + fm][s * 32 + fq];
#pragma unroll
    for (int j = 0; j < 8; ++j) {
      bf16x8 bf = *(const bf16x8*)&Bs[wcol * 128 + j * 16 + fm][fq];
      acc2[j] = MFMA(af, bf, acc2[j]);
    }
  }

  if (mode == 1) {
    // ---- fused q softmax-kernel: row max over M, exp, bf16 store ----
    float m4[4] = {-3.0e38f, -3.0e38f, -3.0e38f, -3.0e38f};
#pragma unroll
    for (int j = 0; j < 8; ++j)
#pragma unroll
      for (int r = 0; r < 4; ++r) m4[r] = fmaxf(m4[r], acc2[j][r]);
#pragma unroll
    for (int o = 1; o < 16; o <<= 1)
#pragma unroll
      for (int r = 0; r < 4; ++r) m4[r] = fmaxf(m4[r], __shfl_xor(m4[r], o, 64));
    if (fm == 0) {
#pragma unroll
      for (int r = 0; r < 4; ++r) mred[wcol][wrow * 16 + rowq + r] = m4[r];
    }
    __syncthreads();
#pragma unroll
    for (int j = 0; j < 8; ++j) {
      const int col = wcol * 128 + j * 16 + fm;
#pragma unroll
      for (int r = 0; r < 4; ++r) {
        const int row = wrow * 16 + rowq + r;
        float mxr = fmaxf(mred[0][row], mred[1][row]);
        float dgr = 0.03125f * (dred[0][row] + dred[1][row]);
        float v = 0.0625f * (__expf(acc2[j][r] - dgr - mxr) + 1e-6f);
        qp[(long long)(row0 + row) * 256 + col] = f2bf(v);
      }
    }
  } else {
    // ---- k: write xp f32 + per-batch max for the global-max pass ----
    float mx = -3.0e38f;
#pragma unroll
    for (int j = 0; j < 8; ++j) {
      int col = wcol * 128 + j * 16 + fm;
#pragma unroll
      for (int r = 0; r < 4; ++r) {
        float v = acc2[j][r];
        xp[(long long)(row0 + wrow * 16 + rowq + r) * 256 + col] = v;
        mx = fmaxf(mx, v);
      }
    }
#pragma unroll
    for (int o = 32; o > 0; o >>= 1) mx = fmaxf(mx, __shfl_xor(mx, o, 64));
    if (lane == 0) wred[wid] = mx;
    __syncthreads();
    if (t == 0) {
      float m = fmaxf(fmaxf(wred[0], wred[1]), fmaxf(wred[2], wred[3]));
      atomicMax(mxk + (row0 >> 11), encf(m));
    }
  }
}

// ---------------------------------------------------------------------------
// kvs_raw_split: part[z][m][i] = kp_chunk^T @ Xv_chunk over 256-row chunks.
// kp = exp(xp-diag-mx) fused in transpose-staging; Xv read f32 and converted
// inline; ksum accumulated by ny==0 blocks.
// grid (4 mx, 4 ny, 32 = b*8+kc) = 512 blocks -> 2 blocks/CU.
// ---------------------------------------------------------------------------
__global__ __launch_bounds__(256, 2) void kvs_raw_split(
    const float* __restrict__ xp, const float* __restrict__ Xv,
    const float* __restrict__ diag_k, const u32* __restrict__ mxk,
    float* __restrict__ part, float* __restrict__ ksum) {
  __shared__ union USM {
    struct { u16 As[64][40]; u16 Bs[64][40]; } s;
    float ksbuf[32][65];
  } sm;
  const int mxt = blockIdx.x, ny = blockIdx.y, z = blockIdx.z;
  const int b = z >> 3, kc = z & 7;
  const long long l0 = (long long)b * 2048 + kc * 256;
  const int t = threadIdx.x;
  const int lane = t & 63, wid = t >> 6;
  const int wrow = wid >> 1, wcol = wid & 1;
  const int fm = lane & 15, fq = (lane >> 4) * 8, rowq = (lane >> 4) * 4;
  const float mxv = decf(mxk[b]);
  const int sr = t >> 3, sc = (t & 7) * 8;
  f32x4 acc[2][2] = {};
  float ksp[8] = {};
  long long lrow = l0 + sr;
  float4 x0 = *(const float4*)(xp + lrow * 256 + mxt * 64 + sc);
  float4 x1 = *(const float4*)(xp + lrow * 256 + mxt * 64 + sc + 4);
  float4 v0 = *(const float4*)(Xv + lrow * 256 + ny * 64 + sc);
  float4 v1 = *(const float4*)(Xv + lrow * 256 + ny * 64 + sc + 4);
  float dgl = diag_k[lrow];
  for (int s = 0; s < 8; ++s) {
    float xv[8] = {x0.x, x0.y, x0.z, x0.w, x1.x, x1.y, x1.z, x1.w};
    float vv[8] = {v0.x, v0.y, v0.z, v0.w, v1.x, v1.y, v1.z, v1.w};
    u16 kpv[8], vpv[8];
#pragma unroll
    for (int j = 0; j < 8; ++j) {
      float v = 0.0625f * (__expf(xv[j] - dgl - mxv) + 1e-6f);
      kpv[j] = f2bf(v);
      ksp[j] += bf2f(kpv[j]);
      vpv[j] = f2bf(vv[j]);
    }
    __syncthreads();
#pragma unroll
    for (int j = 0; j < 8; ++j) {
      sm.s.As[sc + j][sr] = kpv[j];
      sm.s.Bs[sc + j][sr] = vpv[j];
    }
    __syncthreads();
    if (s < 7) {
      lrow = l0 + (s + 1) * 32 + sr;
      x0 = *(const float4*)(xp + lrow * 256 + mxt * 64 + sc);
      x1 = *(const float4*)(xp + lrow * 256 + mxt * 64 + sc + 4);
      v0 = *(const float4*)(Xv + lrow * 256 + ny * 64 + sc);
      v1 = *(const float4*)(Xv + lrow * 256 + ny * 64 + sc + 4);
      dgl = diag_k[lrow];
    }
    bf16x8 a0 = *(const bf16x8*)&sm.s.As[wrow * 32 + fm][fq];
    bf16x8 a1 = *(const bf16x8*)&sm.s.As[wrow * 32 + 16 + fm][fq];
    bf16x8 b0 = *(const bf16x8*)&sm.s.Bs[wcol * 32 + fm][fq];
    bf16x8 b1 = *(const bf16x8*)&sm.s.Bs[wcol * 32 + 16 + fm][fq];
    acc[0][0] = MFMA(a0, b0, acc[0][0]);
    acc[0][1] = MFMA(a0, b1, acc[0][1]);
    acc[1][0] = MFMA(a1, b0, acc[1][0]);
    acc[1][1] = MFMA(a1, b1, acc[1][1]);
  }
#pragma unroll
  for (int mt = 0; mt < 2; ++mt)
#pragma unroll
    for (int nt = 0; nt < 2; ++nt)
#pragma unroll
      for (int r = 0; r < 4; ++r)
        part[(long long)z * 65536 +
             (long long)(mxt * 64 + wrow * 32 + mt * 16 + rowq + r) * 256 +
             ny * 64 + wcol * 32 + nt * 16 + fm] = acc[mt][nt][r];
  __syncthreads();
#pragma unroll
  for (int j = 0; j < 8; ++j) sm.ksbuf[sr][sc + j] = ksp[j];
  __syncthreads();
  if (ny == 0 && t < 64) {
    float ssum = 0.0f;
    for (int r = 0; r < 32; ++r) ssum += sm.ksbuf[r][t];
    atomicAdd(ksum + b * 256 + mxt * 64 + t, ssum);
  }
}

// ---------------------------------------------------------------------------
// kvsw: kvsWT[b][o][m] = bf16( sum_i WWT[o][i] * (sum_kc part[b*8+kc][m][i])
//                              + bw[o]*ksum[b][m] )
// ---------------------------------------------------------------------------
__global__ __launch_bounds__(256) void kvsw(
    const u16* __restrict__ WWT, const float* __restrict__ part,
    const float* __restrict__ ksum, const float* __restrict__ bw,
    u16* __restrict__ kvsWT) {
  __shared__ u16 As[64][40];
  __shared__ u16 Bs[64][40];
  const int o0 = blockIdx.x * 64, m0 = blockIdx.y * 64, b = blockIdx.z;
  const int t = threadIdx.x;
  const int lane = t & 63, wid = t >> 6;
  const int wm = (wid >> 1) * 32, wn = (wid & 1) * 32;
  const int fm = lane & 15, fq = (lane >> 4) * 8, rowq = (lane >> 4) * 4;
  const int arow = t >> 2, acol = (t & 3) * 8;
  f32x4 acc[2][2] = {};
  for (int it = 0; it < 8; ++it) {
    int k0 = it * 32;
    uint4 av = *(const uint4*)(WWT + (o0 + arow) * 256 + k0 + acol);
    float4 s0 = {0, 0, 0, 0}, s1 = {0, 0, 0, 0};
#pragma unroll
    for (int kc = 0; kc < 8; ++kc) {
      const float* pp = part + (long long)(b * 8 + kc) * 65536 + (long long)(m0 + arow) * 256 + k0 + acol;
      float4 u0 = *(const float4*)(pp);
      float4 u1 = *(const float4*)(pp + 4);
      s0.x += u0.x; s0.y += u0.y; s0.z += u0.z; s0.w += u0.w;
      s1.x += u1.x; s1.y += u1.y; s1.z += u1.z; s1.w += u1.w;
    }
    __syncthreads();
    *(uint4*)&As[arow][acol] = av;
    u16* bp = &Bs[arow][acol];
    bp[0] = f2bf(s0.x); bp[1] = f2bf(s0.y); bp[2] = f2bf(s0.z); bp[3] = f2bf(s0.w);
    bp[4] = f2bf(s1.x); bp[5] = f2bf(s1.y); bp[6] = f2bf(s1.z); bp[7] = f2bf(s1.w);
    __syncthreads();
    bf16x8 a0 = *(const bf16x8*)&As[wm + fm][fq];
    bf16x8 a1 = *(const bf16x8*)&As[wm + 16 + fm][fq];
    bf16x8 b0 = *(const bf16x8*)&Bs[wn + fm][fq];
    bf16x8 b1 = *(const bf16x8*)&Bs[wn + 16 + fm][fq];
    acc[0][0] = MFMA(a0, b0, acc[0][0]);
    acc[0][1] = MFMA(a0, b1, acc[0][1]);
    acc[1][0] = MFMA(a1, b0, acc[1][0]);
    acc[1][1] = MFMA(a1, b1, acc[1][1]);
  }
#pragma unroll
  for (int mt = 0; mt < 2; ++mt)
#pragma unroll
    for (int nt = 0; nt < 2; ++nt) {
      int col = m0 + wn + nt * 16 + fm;
      float ksv = ksum[b * 256 + col];
#pragma unroll
      for (int r = 0; r < 4; ++r) {
        int row = o0 + wm + mt * 16 + rowq + r;
        float v = acc[mt][nt][r] + bw[row] * ksv;
        kvsWT[(long long)b * 65536 + (long long)row * 256 + col] = f2bf(v);
      }
    }
}

// ---------------------------------------------------------------------------
// numout: qp (bf16) precomputed by projrot2 q-mode. A-fragments loaded
// directly from global (per-lane 16B contiguous); den from the same bf16
// values. 16-row tiles, grid (128,1,4), 4 blocks/CU.
// out = (qp @ kvsWT^T)/den + bo.
// ---------------------------------------------------------------------------
__global__ __launch_bounds__(256, 4) void numout(
    const u16* __restrict__ qp, const float* __restrict__ ksum,
    const u16* __restrict__ kvsWT, const float* __restrict__ bo,
    float* __restrict__ out) {
  __shared__ float ksm[256], dsh[16];
  const int row0 = blockIdx.x * 16;
  const int b = blockIdx.z;
  const long long qrow = (long long)b * 2048 + row0;
  const int t = threadIdx.x;
  const int lane = t & 63, wid = t >> 6;
  const int fm = lane & 15, fq = (lane >> 4) * 8, rowq = (lane >> 4) * 4;

  // A frags: direct per-lane global loads, all 8 K-steps hoisted
  const u16* qa = qp + (qrow + fm) * 256 + fq;
  bf16x8 af[8];
#pragma unroll
  for (int it = 0; it < 8; ++it) af[it] = *(const bf16x8*)(qa + it * 32);

  // B first buffer (register dbuf, lookahead 1)
  const u16* kvb = kvsWT + (long long)b * 65536 + (long long)(wid * 64 + fm) * 256 + fq;
  bf16x8 bb[2][4];
#pragma unroll
  for (int j = 0; j < 4; ++j) bb[0][j] = *(const bf16x8*)(kvb + j * 4096);

  // den inputs
  ksm[t] = ksum[b * 256 + t];
  const int prow = t >> 4, pc0 = (t & 15) * 16;
  const u16* qr = qp + (qrow + prow) * 256 + pc0;
  uint4 u0 = *(const uint4*)(qr);
  uint4 u1 = *(const uint4*)(qr + 8);
  __syncthreads();  // ksm visible

  float denp = 0.0f;
  u32 uu[8] = {u0.x, u0.y, u0.z, u0.w, u1.x, u1.y, u1.z, u1.w};
#pragma unroll
  for (int j = 0; j < 8; ++j) {
    denp += bf2f((u16)(uu[j] & 0xffffu)) * ksm[pc0 + 2 * j];
    denp += bf2f((u16)(uu[j] >> 16)) * ksm[pc0 + 2 * j + 1];
  }
#pragma unroll
  for (int o = 1; o < 16; o <<= 1) denp += __shfl_xor(denp, o, 64);
  if ((t & 15) == 0) dsh[prow] = denp;

  // GEMM
  f32x4 acc[4] = {};
#pragma unroll
  for (int it = 0; it < 8; ++it) {
    if (it < 7) {
#pragma unroll
      for (int j = 0; j < 4; ++j)
        bb[(it + 1) & 1][j] = *(const bf16x8*)(kvb + j * 4096 + (it + 1) * 32);
    }
#pragma unroll
    for (int j = 0; j < 4; ++j) acc[j] = MFMA(af[it], bb[it & 1][j], acc[j]);
  }
  __syncthreads();  // dsh visible
#pragma unroll
  for (int j = 0; j < 4; ++j) {
    int col = wid * 64 + j * 16 + fm;
    float bb2 = bo[col];
#pragma unroll
    for (int r = 0; r < 4; ++r) {
      int l = rowq + r;
      out[(qrow + l) * 256 + col] = acc[j][r] / dsh[l] + bb2;
    }
  }
}

// ---------------------------------------------------------------------------
extern "C" void kernel_launch(void* const* d_in, const int* in_sizes, int n_in,
                              void* d_out, int out_size, void* d_ws, size_t ws_size,
                              hipStream_t stream) {
  (void)in_sizes; (void)n_in; (void)out_size; (void)ws_size;
  const float* query = (const float*)d_in[0];
  const float* key = (const float*)d_in[1];
  const float* value = (const float*)d_in[2];
  // d_in[3] = mask: all-ones, unused
  const float* Wq = (const float*)d_in[4];
  const float* bq = (const float*)d_in[5];
  const float* Wk = (const float*)d_in[6];
  const float* bk = (const float*)d_in[7];
  const float* Wv = (const float*)d_in[8];
  const float* bv = (const float*)d_in[9];
  const float* Wo = (const float*)d_in[10];
  const float* bo = (const float*)d_in[11];
  const float* proj = (const float*)d_in[12];
  const float* pos = (const float*)d_in[13];

  char* w = (char*)d_ws;  // ~26.2 MB used
  u16* qp = (u16*)(w);                        // 4 MB (bf16 q-features)
  float* xp = (float*)(w + (8 << 20));        // 8 MB (k-features f32)
  float* part = (float*)(w + (16 << 20));     // 8 MB (32 x 256 x 256 f32)
  u16* kvsWT = (u16*)(w + (24 << 20));        // 512 KB
  u16* WqT = (u16*)(w + (25 << 20));          // 128 KB each
  u16* WkT = WqT + 65536;
  u16* projb = WkT + 65536;
  u16* WWT = projb + 65536;
  float* diag_k = (float*)(w + (26 << 20));   // 32 KB
  float* ksum = diag_k + 8192;                // 4 KB
  float* bw = ksum + 1024;                    // 1 KB
  u32* mxk = (u32*)(bw + 256);                // 16 B

  prep_w<<<dim3(8, 8, 4), dim3(32, 8), 0, stream>>>(Wq, Wk, Wv, Wo, proj, bv,
                                                    WqT, WkT, projb, WWT, bw,
                                                    ksum, mxk);
  projrot2<<<dim3(256, 1, 2), dim3(256), 0, stream>>>(
      query, key, WqT, WkT, bq, bk, pos, projb, diag_k, qp, xp, mxk);
  kvs_raw_split<<<dim3(4, 4, 32), dim3(256), 0, stream>>>(xp, value, diag_k, mxk,
                                                          part, ksum);
  kvsw<<<dim3(4, 4, 4), dim3(256), 0, stream>>>(WWT, part, ksum, bw, kvsWT);
  numout<<<dim3(128, 1, 4), dim3(256), 0, stream>>>(qp, ksum, kvsWT, bo,
                                                    (float*)d_out);
}

// Round 6
// 81.118 us; speedup vs baseline: 1.2692x; 1.0081x over previous
//
#include <hip/hip_runtime.h>

typedef unsigned short u16;
typedef unsigned int u32;
typedef __bf16 bf16x8 __attribute__((ext_vector_type(8)));
typedef float f32x4 __attribute__((ext_vector_type(4)));

__device__ __forceinline__ float bf2f(u16 u) { return __uint_as_float(((u32)u) << 16); }
__device__ __forceinline__ u16 f2bf(float f) {
  u32 x = __float_as_uint(f);
  x += 0x7fffu + ((x >> 16) & 1u);
  return (u16)(x >> 16);
}
// monotone float<->uint encoding for atomicMax on floats (finite values)
__device__ __forceinline__ u32 encf(float x) {
  u32 u = __float_as_uint(x);
  return (u >> 31) ? ~u : (u | 0x80000000u);
}
__device__ __forceinline__ float decf(u32 e) {
  return (e >> 31) ? __uint_as_float(e & 0x7fffffffu) : __uint_as_float(~e);
}

#define MFMA(a, b, c) __builtin_amdgcn_mfma_f32_16x16x32_bf16(a, b, c, 0, 0, 0)

// ---------------------------------------------------------------------------
// prep_w: z=0: Wq->WqT bf16 transposed; z=1: Wk->WkT; z=2: proj->projb copy;
// z=3: x<4&&y<4: WWT[o][i] = sum_d Wo[d][o]*Wv[i][d]  (bf16, from f32 inputs)
//      x==4&&y==0: bw[o] = sum_d bv[d]*Wo[d][o]; zero ksum; zero mxk.
// ---------------------------------------------------------------------------
__global__ __launch_bounds__(256) void prep_w(
    const float* Wq, const float* Wk, const float* Wv, const float* Wo,
    const float* proj, const float* bv,
    u16* WqT, u16* WkT, u16* projb, u16* WWT, float* bw,
    float* __restrict__ ksum, u32* __restrict__ mxk) {
  __shared__ u16 tsh[32][33];
  __shared__ u16 As[64][40];
  __shared__ u16 Bs[64][40];
  const int z = blockIdx.z;
  const int x = threadIdx.x, y = threadIdx.y;
  const int tid = y * 32 + x;
  if (z < 2) {
    const float* s = z == 0 ? Wq : Wk;
    u16* d = z == 0 ? WqT : WkT;
    int r0 = blockIdx.y * 32, c0 = blockIdx.x * 32;
#pragma unroll
    for (int i = 0; i < 32; i += 8) tsh[y + i][x] = f2bf(s[(r0 + y + i) * 256 + c0 + x]);
    __syncthreads();
#pragma unroll
    for (int i = 0; i < 32; i += 8) d[(c0 + y + i) * 256 + r0 + x] = tsh[x][y + i];
    return;
  }
  if (z == 2) {
    int r0 = blockIdx.y * 32, c0 = blockIdx.x * 32;
#pragma unroll
    for (int i = 0; i < 32; i += 8)
      projb[(r0 + y + i) * 256 + c0 + x] = f2bf(proj[(r0 + y + i) * 256 + c0 + x]);
    return;
  }
  // z == 3
  if (blockIdx.x < 4 && blockIdx.y < 4) {
    const int o0 = blockIdx.x * 64, i0 = blockIdx.y * 64;
    const int lane = tid & 63, wid = tid >> 6;
    const int wm = (wid >> 1) * 32, wn = (wid & 1) * 32;
    const int fm = lane & 15, fq = (lane >> 4) * 8, rowq = (lane >> 4) * 4;
    const int dr = tid >> 3, oc = (tid & 7) * 8;
    const int ir = tid >> 2, dc = (tid & 3) * 8;
    f32x4 acc[2][2] = {};
    for (int it = 0; it < 8; ++it) {
      int d0 = it * 32;
      float4 w0 = *(const float4*)(Wo + (d0 + dr) * 256 + o0 + oc);
      float4 w1 = *(const float4*)(Wo + (d0 + dr) * 256 + o0 + oc + 4);
      float4 v0 = *(const float4*)(Wv + (i0 + ir) * 256 + d0 + dc);
      float4 v1 = *(const float4*)(Wv + (i0 + ir) * 256 + d0 + dc + 4);
      __syncthreads();
      float wv[8] = {w0.x, w0.y, w0.z, w0.w, w1.x, w1.y, w1.z, w1.w};
#pragma unroll
      for (int j = 0; j < 8; ++j) As[oc + j][dr] = f2bf(wv[j]);
      u16* bp = &Bs[ir][dc];
      bp[0] = f2bf(v0.x); bp[1] = f2bf(v0.y); bp[2] = f2bf(v0.z); bp[3] = f2bf(v0.w);
      bp[4] = f2bf(v1.x); bp[5] = f2bf(v1.y); bp[6] = f2bf(v1.z); bp[7] = f2bf(v1.w);
      __syncthreads();
      bf16x8 a0 = *(const bf16x8*)&As[wm + fm][fq];
      bf16x8 a1 = *(const bf16x8*)&As[wm + 16 + fm][fq];
      bf16x8 b0 = *(const bf16x8*)&Bs[wn + fm][fq];
      bf16x8 b1 = *(const bf16x8*)&Bs[wn + 16 + fm][fq];
      acc[0][0] = MFMA(a0, b0, acc[0][0]);
      acc[0][1] = MFMA(a0, b1, acc[0][1]);
      acc[1][0] = MFMA(a1, b0, acc[1][0]);
      acc[1][1] = MFMA(a1, b1, acc[1][1]);
    }
#pragma unroll
    for (int mt = 0; mt < 2; ++mt)
#pragma unroll
      for (int nt = 0; nt < 2; ++nt)
#pragma unroll
        for (int r = 0; r < 4; ++r)
          WWT[(o0 + wm + mt * 16 + rowq + r) * 256 + i0 + wn + nt * 16 + fm] =
              f2bf(acc[mt][nt][r]);
    return;
  }
  if (blockIdx.x == 4 && blockIdx.y == 0) {
    float s = 0.0f;
    for (int d = 0; d < 256; ++d) s = fmaf(bv[d], Wo[d * 256 + tid], s);
    bw[tid] = s;
    for (int i = tid; i < 1024; i += 256) ksum[i] = 0.0f;
    if (tid < 4) mxk[tid] = 0u;
  }
}

// ---------------------------------------------------------------------------
// projrot2: z=0 key, z=1 query. 32-row tiles, grid (256,1,2).
// Both GEMM operands via LDS (proven round-5 structure): reg-load chunk ->
// barrier -> LDS write -> barrier -> ds_read_b128 -> MFMA, next chunk's
// global loads issued under the MFMAs.
//  - mode 0 (k): xp f32 + diag_k + per-batch atomicMax.
//  - mode 1 (q): fused softmax-kernel -> qp bf16 (row-max block-local).
// ---------------------------------------------------------------------------
__global__ __launch_bounds__(256, 3) void projrot2(
    const float* __restrict__ Xq, const float* __restrict__ Xk,
    const u16* __restrict__ WqT, const u16* __restrict__ WkT,
    const float* __restrict__ bq, const float* __restrict__ bk,
    const float* __restrict__ pos, const u16* __restrict__ projb,
    float* __restrict__ diag_k, u16* __restrict__ qp,
    float* __restrict__ xp, u32* __restrict__ mxk) {
  const int mode = blockIdx.z;  // 0=k, 1=q
  const float* X = mode ? Xq : Xk;
  const u16* W = mode ? WqT : WkT;  // [outcol][k] bf16
  const float* bias = mode ? bq : bk;
  __shared__ u16 As[32][40];    // 2.5 KB: X chunk (32 rows x 32 k)
  __shared__ u16 Bs[256][40];   // 20 KB: W/proj chunk (256 cols x 32 k)
  __shared__ u16 cbuf[32][264]; // 16.9 KB rotated bf16
  __shared__ float dred[2][32];
  __shared__ float mred[2][32];
  __shared__ float wred[4];
  const int row0 = blockIdx.x * 32;
  const int t = threadIdx.x;
  const int lane = t & 63, wid = t >> 6;
  const int wrow = wid & 1, wcol = wid >> 1;  // 16 rows x 128 cols per wave
  const int fm = lane & 15, fq = (lane >> 4) * 8, rowq = (lane >> 4) * 4;
  // staging indices
  const int ar = t >> 3, ak = (t & 7) * 4;  // A: row, k-quad

  // ---- GEMM1: X @ W^T, both operands staged through LDS ----
  f32x4 acc[8] = {};
  float4 av = *(const float4*)(X + (long long)(row0 + ar) * 256 + ak);
  uint4 bv0 = ((const uint4*)(W + (long long)t * 256))[0];
  uint4 bv1 = ((const uint4*)(W + (long long)t * 256))[1];
  uint4 bv2 = ((const uint4*)(W + (long long)t * 256))[2];
  uint4 bv3 = ((const uint4*)(W + (long long)t * 256))[3];
  for (int s = 0; s < 8; ++s) {
    __syncthreads();  // prev-iter ds_reads done
    As[ar][ak] = f2bf(av.x); As[ar][ak + 1] = f2bf(av.y);
    As[ar][ak + 2] = f2bf(av.z); As[ar][ak + 3] = f2bf(av.w);
    uint4* bsp = (uint4*)&Bs[t][0];
    bsp[0] = bv0; bsp[1] = bv1; bsp[2] = bv2; bsp[3] = bv3;
    __syncthreads();  // staging visible
    if (s < 7) {
      const int k1 = (s + 1) * 32;
      av = *(const float4*)(X + (long long)(row0 + ar) * 256 + k1 + ak);
      const uint4* wn = (const uint4*)(W + (long long)t * 256 + k1);
      bv0 = wn[0]; bv1 = wn[1]; bv2 = wn[2]; bv3 = wn[3];
    }
    bf16x8 af = *(const bf16x8*)&As[wrow * 16 + fm][fq];
#pragma unroll
    for (int j = 0; j < 8; ++j) {
      bf16x8 bf = *(const bf16x8*)&Bs[wcol * 128 + j * 16 + fm][fq];
      acc[j] = MFMA(af, bf, acc[j]);
    }
  }

  // ---- epilogue: bias into acc, diag partials (pre-rotary) ----
  float dsum[4] = {};
#pragma unroll
  for (int j = 0; j < 8; ++j) {
    float bb2 = bias[wcol * 128 + j * 16 + fm];
#pragma unroll
    for (int r = 0; r < 4; ++r) {
      float v = acc[j][r] + bb2;
      acc[j][r] = v;
      dsum[r] += v * v;
    }
  }
#pragma unroll
  for (int o = 1; o < 16; o <<= 1)
#pragma unroll
    for (int r = 0; r < 4; ++r) dsum[r] += __shfl_xor(dsum[r], o, 64);
  if (fm == 0) {
#pragma unroll
    for (int r = 0; r < 4; ++r) dred[wcol][wrow * 16 + rowq + r] = dsum[r];
  }
  __syncthreads();  // dred visible
  if (mode == 0 && t < 32) diag_k[row0 + t] = 0.03125f * (dred[0][t] + dred[1][t]);

  // ---- rotary in registers (partner col = lane^1), pos direct global ----
#pragma unroll
  for (int j = 0; j < 8; ++j) {
    const int c = wcol * 128 + j * 16 + fm;
#pragma unroll
    for (int r = 0; r < 4; ++r) {
      const int row = wrow * 16 + rowq + r;
      const int l = (row0 + row) & 2047;
      float v = acc[j][r];
      float prt = __shfl_xor(v, 1, 64);
      float x2 = (fm & 1) ? prt : -prt;
      float2 cs = *(const float2*)(pos + (long long)l * 256 + (c & ~1));
      // cs.x = sin (even col), cs.y = cos (odd col)
      cbuf[row][c] = f2bf(0.25f * (v * cs.y + x2 * cs.x));
    }
  }

  // ---- GEMM2: cbuf(rotated) @ projb^T, B staged through LDS (reuse Bs) ----
  f32x4 acc2[8] = {};
  uint4 pv0 = ((const uint4*)(projb + (long long)t * 256))[0];
  uint4 pv1 = ((const uint4*)(projb + (long long)t * 256))[1];
  uint4 pv2 = ((const uint4*)(projb + (long long)t * 256))[2];
  uint4 pv3 = ((const uint4*)(projb + (long long)t * 256))[3];
  for (int s = 0; s < 8; ++s) {
    __syncthreads();  // prev-iter ds_reads done (and cbuf writes on s=0)
    uint4* bsp = (uint4*)&Bs[t][0];
    bsp[0] = pv0; bsp[1] = pv1; bsp[2] = pv2; bsp[3] = pv3;
    __syncthreads();  // staging visible
    if (s < 7) {
      const uint4* pn = (const uint4*)(projb + (long long)t * 256 + (s + 1) * 32);
      pv0 = pn[0]; pv1 = pn[1]; pv2 = pn[2]; pv3 = pn[3];
    }
    bf16x8 af = *(const bf16x8*)&cbuf[wrow * 16 + fm][s * 32 + fq];
#pragma unroll
    for (int j = 0; j < 8; ++j) {
      bf16x8 bf = *(const bf16x8*)&Bs[wcol * 128 + j * 16 + fm][fq];
      acc2[j] = MFMA(af, bf, acc2[j]);
    }
  }

  if (mode == 1) {
    // ---- fused q softmax-kernel: row max over M, exp, bf16 store ----
    float m4[4] = {-3.0e38f, -3.0e38f, -3.0e38f, -3.0e38f};
#pragma unroll
    for (int j = 0; j < 8; ++j)
#pragma unroll
      for (int r = 0; r < 4; ++r) m4[r] = fmaxf(m4[r], acc2[j][r]);
#pragma unroll
    for (int o = 1; o < 16; o <<= 1)
#pragma unroll
      for (int r = 0; r < 4; ++r) m4[r] = fmaxf(m4[r], __shfl_xor(m4[r], o, 64));
    if (fm == 0) {
#pragma unroll
      for (int r = 0; r < 4; ++r) mred[wcol][wrow * 16 + rowq + r] = m4[r];
    }
    __syncthreads();
#pragma unroll
    for (int j = 0; j < 8; ++j) {
      const int col = wcol * 128 + j * 16 + fm;
#pragma unroll
      for (int r = 0; r < 4; ++r) {
        const int row = wrow * 16 + rowq + r;
        float mxr = fmaxf(mred[0][row], mred[1][row]);
        float dgr = 0.03125f * (dred[0][row] + dred[1][row]);
        float v = 0.0625f * (__expf(acc2[j][r] - dgr - mxr) + 1e-6f);
        qp[(long long)(row0 + row) * 256 + col] = f2bf(v);
      }
    }
  } else {
    // ---- k: write xp f32 + per-batch max for the global-max pass ----
    float mx = -3.0e38f;
#pragma unroll
    for (int j = 0; j < 8; ++j) {
      int col = wcol * 128 + j * 16 + fm;
#pragma unroll
      for (int r = 0; r < 4; ++r) {
        float v = acc2[j][r];
        xp[(long long)(row0 + wrow * 16 + rowq + r) * 256 + col] = v;
        mx = fmaxf(mx, v);
      }
    }
#pragma unroll
    for (int o = 32; o > 0; o >>= 1) mx = fmaxf(mx, __shfl_xor(mx, o, 64));
    if (lane == 0) wred[wid] = mx;
    __syncthreads();
    if (t == 0) {
      float m = fmaxf(fmaxf(wred[0], wred[1]), fmaxf(wred[2], wred[3]));
      atomicMax(mxk + (row0 >> 11), encf(m));
    }
  }
}

// ---------------------------------------------------------------------------
// kvs_raw_split: part[z][m][i] = kp_chunk^T @ Xv_chunk over 512-row chunks
// (round-0 config: kc=4, part 4 MB). kp = exp(xp-diag-mx) fused in
// transpose-staging; Xv read f32 and converted inline; ksum accumulated by
// ny==0 blocks. grid (4 mx, 4 ny, 16 = b*4+kc).
// ---------------------------------------------------------------------------
__global__ __launch_bounds__(256) void kvs_raw_split(
    const float* __restrict__ xp, const float* __restrict__ Xv,
    const float* __restrict__ diag_k, const u32* __restrict__ mxk,
    float* __restrict__ part, float* __restrict__ ksum) {
  __shared__ union USM {
    struct { u16 As[64][40]; u16 Bs[64][40]; } s;
    float ksbuf[32][65];
  } sm;
  const int mxt = blockIdx.x, ny = blockIdx.y, z = blockIdx.z;
  const int b = z >> 2, kc = z & 3;
  const long long l0 = (long long)b * 2048 + kc * 512;
  const int t = threadIdx.x;
  const int lane = t & 63, wid = t >> 6;
  const int wrow = wid >> 1, wcol = wid & 1;
  const int fm = lane & 15, fq = (lane >> 4) * 8, rowq = (lane >> 4) * 4;
  const float mxv = decf(mxk[b]);
  const int sr = t >> 3, sc = (t & 7) * 8;
  f32x4 acc[2][2] = {};
  float ksp[8] = {};
  long long lrow = l0 + sr;
  float4 x0 = *(const float4*)(xp + lrow * 256 + mxt * 64 + sc);
  float4 x1 = *(const float4*)(xp + lrow * 256 + mxt * 64 + sc + 4);
  float4 v0 = *(const float4*)(Xv + lrow * 256 + ny * 64 + sc);
  float4 v1 = *(const float4*)(Xv + lrow * 256 + ny * 64 + sc + 4);
  float dgl = diag_k[lrow];
  for (int s = 0; s < 16; ++s) {
    float xv[8] = {x0.x, x0.y, x0.z, x0.w, x1.x, x1.y, x1.z, x1.w};
    float vv[8] = {v0.x, v0.y, v0.z, v0.w, v1.x, v1.y, v1.z, v1.w};
    u16 kpv[8], vpv[8];
#pragma unroll
    for (int j = 0; j < 8; ++j) {
      float v = 0.0625f * (__expf(xv[j] - dgl - mxv) + 1e-6f);
      kpv[j] = f2bf(v);
      ksp[j] += bf2f(kpv[j]);
      vpv[j] = f2bf(vv[j]);
    }
    __syncthreads();
#pragma unroll
    for (int j = 0; j < 8; ++j) {
      sm.s.As[sc + j][sr] = kpv[j];
      sm.s.Bs[sc + j][sr] = vpv[j];
    }
    __syncthreads();
    if (s < 15) {
      lrow = l0 + (s + 1) * 32 + sr;
      x0 = *(const float4*)(xp + lrow * 256 + mxt * 64 + sc);
      x1 = *(const float4*)(xp + lrow * 256 + mxt * 64 + sc + 4);
      v0 = *(const float4*)(Xv + lrow * 256 + ny * 64 + sc);
      v1 = *(const float4*)(Xv + lrow * 256 + ny * 64 + sc + 4);
      dgl = diag_k[lrow];
    }
    bf16x8 a0 = *(const bf16x8*)&sm.s.As[wrow * 32 + fm][fq];
    bf16x8 a1 = *(const bf16x8*)&sm.s.As[wrow * 32 + 16 + fm][fq];
    bf16x8 b0 = *(const bf16x8*)&sm.s.Bs[wcol * 32 + fm][fq];
    bf16x8 b1 = *(const bf16x8*)&sm.s.Bs[wcol * 32 + 16 + fm][fq];
    acc[0][0] = MFMA(a0, b0, acc[0][0]);
    acc[0][1] = MFMA(a0, b1, acc[0][1]);
    acc[1][0] = MFMA(a1, b0, acc[1][0]);
    acc[1][1] = MFMA(a1, b1, acc[1][1]);
  }
#pragma unroll
  for (int mt = 0; mt < 2; ++mt)
#pragma unroll
    for (int nt = 0; nt < 2; ++nt)
#pragma unroll
      for (int r = 0; r < 4; ++r)
        part[(long long)z * 65536 +
             (long long)(mxt * 64 + wrow * 32 + mt * 16 + rowq + r) * 256 +
             ny * 64 + wcol * 32 + nt * 16 + fm] = acc[mt][nt][r];
  __syncthreads();
#pragma unroll
  for (int j = 0; j < 8; ++j) sm.ksbuf[sr][sc + j] = ksp[j];
  __syncthreads();
  if (ny == 0 && t < 64) {
    float ssum = 0.0f;
    for (int r = 0; r < 32; ++r) ssum += sm.ksbuf[r][t];
    atomicAdd(ksum + b * 256 + mxt * 64 + t, ssum);
  }
}

// ---------------------------------------------------------------------------
// kvsw: kvsWT[b][o][m] = bf16( sum_i WWT[o][i] * (sum_kc part[b*4+kc][m][i])
//                              + bw[o]*ksum[b][m] )
// ---------------------------------------------------------------------------
__global__ __launch_bounds__(256) void kvsw(
    const u16* __restrict__ WWT, const float* __restrict__ part,
    const float* __restrict__ ksum, const float* __restrict__ bw,
    u16* __restrict__ kvsWT) {
  __shared__ u16 As[64][40];
  __shared__ u16 Bs[64][40];
  const int o0 = blockIdx.x * 64, m0 = blockIdx.y * 64, b = blockIdx.z;
  const int t = threadIdx.x;
  const int lane = t & 63, wid = t >> 6;
  const int wm = (wid >> 1) * 32, wn = (wid & 1) * 32;
  const int fm = lane & 15, fq = (lane >> 4) * 8, rowq = (lane >> 4) * 4;
  const int arow = t >> 2, acol = (t & 3) * 8;
  f32x4 acc[2][2] = {};
  for (int it = 0; it < 8; ++it) {
    int k0 = it * 32;
    uint4 av = *(const uint4*)(WWT + (o0 + arow) * 256 + k0 + acol);
    float4 s0 = {0, 0, 0, 0}, s1 = {0, 0, 0, 0};
#pragma unroll
    for (int kc = 0; kc < 4; ++kc) {
      const float* pp = part + (long long)(b * 4 + kc) * 65536 + (long long)(m0 + arow) * 256 + k0 + acol;
      float4 u0 = *(const float4*)(pp);
      float4 u1 = *(const float4*)(pp + 4);
      s0.x += u0.x; s0.y += u0.y; s0.z += u0.z; s0.w += u0.w;
      s1.x += u1.x; s1.y += u1.y; s1.z += u1.z; s1.w += u1.w;
    }
    __syncthreads();
    *(uint4*)&As[arow][acol] = av;
    u16* bp = &Bs[arow][acol];
    bp[0] = f2bf(s0.x); bp[1] = f2bf(s0.y); bp[2] = f2bf(s0.z); bp[3] = f2bf(s0.w);
    bp[4] = f2bf(s1.x); bp[5] = f2bf(s1.y); bp[6] = f2bf(s1.z); bp[7] = f2bf(s1.w);
    __syncthreads();
    bf16x8 a0 = *(const bf16x8*)&As[wm + fm][fq];
    bf16x8 a1 = *(const bf16x8*)&As[wm + 16 + fm][fq];
    bf16x8 b0 = *(const bf16x8*)&Bs[wn + fm][fq];
    bf16x8 b1 = *(const bf16x8*)&Bs[wn + 16 + fm][fq];
    acc[0][0] = MFMA(a0, b0, acc[0][0]);
    acc[0][1] = MFMA(a0, b1, acc[0][1]);
    acc[1][0] = MFMA(a1, b0, acc[1][0]);
    acc[1][1] = MFMA(a1, b1, acc[1][1]);
  }
#pragma unroll
  for (int mt = 0; mt < 2; ++mt)
#pragma unroll
    for (int nt = 0; nt < 2; ++nt) {
      int col = m0 + wn + nt * 16 + fm;
      float ksv = ksum[b * 256 + col];
#pragma unroll
      for (int r = 0; r < 4; ++r) {
        int row = o0 + wm + mt * 16 + rowq + r;
        float v = acc[mt][nt][r] + bw[row] * ksv;
        kvsWT[(long long)b * 65536 + (long long)row * 256 + col] = f2bf(v);
      }
    }
}

// ---------------------------------------------------------------------------
// numout: LDS-staged GEMM (round-5 mold applied). qp (bf16) precomputed by
// projrot2 q-mode; A tile (16x32) and B tile (256x32 of kvsWT) staged per
// K-chunk, next chunk prefetched under the MFMAs. den from qp and ksum.
// 16-row tiles, grid (128,1,4), 4 blocks/CU.
// out = (qp @ kvsWT^T)/den + bo.
// ---------------------------------------------------------------------------
__global__ __launch_bounds__(256, 4) void numout(
    const u16* __restrict__ qp, const float* __restrict__ ksum,
    const u16* __restrict__ kvsWT, const float* __restrict__ bo,
    float* __restrict__ out) {
  __shared__ u16 As[16][40];    // 1.25 KB: qp chunk (16 rows x 32 k)
  __shared__ u16 Bs[256][40];   // 20 KB: kvsWT chunk (256 cols x 32 k)
  __shared__ float ksm[256], dsh[16];
  const int row0 = blockIdx.x * 16;
  const int b = blockIdx.z;
  const long long qrow = (long long)b * 2048 + row0;
  const int t = threadIdx.x;
  const int lane = t & 63, wid = t >> 6;
  const int fm = lane & 15, fq = (lane >> 4) * 8, rowq = (lane >> 4) * 4;
  // staging indices: A 2 bf16/thread (u32), B 4x uint4/thread
  const int ar = t >> 4, ak = (t & 15) * 2;

  // prefetch first chunk
  u32 a0 = *(const u32*)(qp + (qrow + ar) * 256 + ak);
  const u16* kvr = kvsWT + (long long)b * 65536 + (long long)t * 256;
  uint4 bv0 = ((const uint4*)kvr)[0];
  uint4 bv1 = ((const uint4*)kvr)[1];
  uint4 bv2 = ((const uint4*)kvr)[2];
  uint4 bv3 = ((const uint4*)kvr)[3];

  // den inputs
  ksm[t] = ksum[b * 256 + t];
  const int prow = t >> 4, pc0 = (t & 15) * 16;
  const u16* qr = qp + (qrow + prow) * 256 + pc0;
  uint4 u0 = *(const uint4*)(qr);
  uint4 u1 = *(const uint4*)(qr + 8);
  __syncthreads();  // ksm visible

  float denp = 0.0f;
  u32 uu[8] = {u0.x, u0.y, u0.z, u0.w, u1.x, u1.y, u1.z, u1.w};
#pragma unroll
  for (int j = 0; j < 8; ++j) {
    denp += bf2f((u16)(uu[j] & 0xffffu)) * ksm[pc0 + 2 * j];
    denp += bf2f((u16)(uu[j] >> 16)) * ksm[pc0 + 2 * j + 1];
  }
#pragma unroll
  for (int o = 1; o < 16; o <<= 1) denp += __shfl_xor(denp, o, 64);
  if ((t & 15) == 0) dsh[prow] = denp;

  // GEMM: both operands through LDS, prefetch under MFMAs
  f32x4 acc[4] = {};
  for (int s = 0; s < 8; ++s) {
    __syncthreads();  // prev-iter ds_reads done (also covers dsh store)
    *(u32*)&As[ar][ak] = a0;
    uint4* bsp = (uint4*)&Bs[t][0];
    bsp[0] = bv0; bsp[1] = bv1; bsp[2] = bv2; bsp[3] = bv3;
    __syncthreads();  // staging visible
    if (s < 7) {
      const int k1 = (s + 1) * 32;
      a0 = *(const u32*)(qp + (qrow + ar) * 256 + k1 + ak);
      const uint4* kn = (const uint4*)(kvr + k1);
      bv0 = kn[0]; bv1 = kn[1]; bv2 = kn[2]; bv3 = kn[3];
    }
    bf16x8 af = *(const bf16x8*)&As[fm][fq];
#pragma unroll
    for (int j = 0; j < 4; ++j) {
      bf16x8 bf = *(const bf16x8*)&Bs[wid * 64 + j * 16 + fm][fq];
      acc[j] = MFMA(af, bf, acc[j]);
    }
  }
#pragma unroll
  for (int j = 0; j < 4; ++j) {
    int col = wid * 64 + j * 16 + fm;
    float bb2 = bo[col];
#pragma unroll
    for (int r = 0; r < 4; ++r) {
      int l = rowq + r;
      out[(qrow + l) * 256 + col] = acc[j][r] / dsh[l] + bb2;
    }
  }
}

// ---------------------------------------------------------------------------
extern "C" void kernel_launch(void* const* d_in, const int* in_sizes, int n_in,
                              void* d_out, int out_size, void* d_ws, size_t ws_size,
                              hipStream_t stream) {
  (void)in_sizes; (void)n_in; (void)out_size; (void)ws_size;
  const float* query = (const float*)d_in[0];
  const float* key = (const float*)d_in[1];
  const float* value = (const float*)d_in[2];
  // d_in[3] = mask: all-ones, unused
  const float* Wq = (const float*)d_in[4];
  const float* bq = (const float*)d_in[5];
  const float* Wk = (const float*)d_in[6];
  const float* bk = (const float*)d_in[7];
  const float* Wv = (const float*)d_in[8];
  const float* bv = (const float*)d_in[9];
  const float* Wo = (const float*)d_in[10];
  const float* bo = (const float*)d_in[11];
  const float* proj = (const float*)d_in[12];
  const float* pos = (const float*)d_in[13];

  char* w = (char*)d_ws;  // ~22 MB used
  u16* qp = (u16*)(w);                        // 4 MB (bf16 q-features)
  float* xp = (float*)(w + (8 << 20));        // 8 MB (k-features f32)
  float* part = (float*)(w + (16 << 20));     // 4 MB (16 x 256 x 256 f32)
  u16* kvsWT = (u16*)(w + (20 << 20));        // 512 KB
  u16* WqT = (u16*)(w + (21 << 20));          // 128 KB each
  u16* WkT = WqT + 65536;
  u16* projb = WkT + 65536;
  u16* WWT = projb + 65536;
  float* diag_k = (float*)(w + (22 << 20));   // 32 KB
  float* ksum = diag_k + 8192;                // 4 KB
  float* bw = ksum + 1024;                    // 1 KB
  u32* mxk = (u32*)(bw + 256);                // 16 B

  prep_w<<<dim3(8, 8, 4), dim3(32, 8), 0, stream>>>(Wq, Wk, Wv, Wo, proj, bv,
                                                    WqT, WkT, projb, WWT, bw,
                                                    ksum, mxk);
  projrot2<<<dim3(256, 1, 2), dim3(256), 0, stream>>>(
      query, key, WqT, WkT, bq, bk, pos, projb, diag_k, qp, xp, mxk);
  kvs_raw_split<<<dim3(4, 4, 16), dim3(256), 0, stream>>>(xp, value, diag_k, mxk,
                                                          part, ksum);
  kvsw<<<dim3(4, 4, 4), dim3(256), 0, stream>>>(WWT, part, ksum, bw, kvsWT);
  numout<<<dim3(128, 1, 4), dim3(256), 0, stream>>>(qp, ksum, kvsWT, bo,
                                                    (float*)d_out);
}